// Round 23
// baseline (177.274 us; speedup 1.0000x reference)
//
#include <hip/hip_runtime.h>

#define T_SEQ 2048
#define NH    6
#define HD    128
#define CDIM  768
#define NQKV  2304
#define MROWS 8192   // B*T = 4*2048
#define NSLOT 384    // 16 partial chunks per (b,h) * 24
// 1/sqrt(128) * log2(e): folded into Q during gemm1 epilogue
#define QSCL  0.12754011021989615f

typedef __attribute__((ext_vector_type(8)))  short bf16x8;
typedef __attribute__((ext_vector_type(4)))  float f32x4;
typedef __attribute__((ext_vector_type(16))) float f32x16;
typedef __attribute__((ext_vector_type(2)))  int   i32x2;

__device__ __forceinline__ unsigned short f2bf(float f){
  unsigned int u = __builtin_bit_cast(unsigned int, f);
  u += 0x7fffu + ((u >> 16) & 1u);          // round-to-nearest-even
  return (unsigned short)(u >> 16);
}
__device__ __forceinline__ float bf2f(unsigned short h){
  unsigned int u = ((unsigned int)h) << 16;
  return __builtin_bit_cast(float, u);
}
// raw v_exp_f32: computes 2^x in one instruction (no libm slow path)
__device__ __forceinline__ float ex2(float x){
  return __builtin_amdgcn_exp2f(x);
}
// pack 2 f32 -> 2 bf16 in one instr
__device__ __forceinline__ unsigned int cvtpk(float lo, float hi){
  unsigned int r;
  asm("v_cvt_pk_bf16_f32 %0, %1, %2" : "=v"(r) : "v"(lo), "v"(hi));
  return r;
}

// async global->LDS, 16B per lane; LDS dest is wave-uniform base + lane*16
__device__ __forceinline__ void gload_lds16(const void* g, void* l){
  __builtin_amdgcn_global_load_lds(
      (const __attribute__((address_space(1))) unsigned int*)g,
      (__attribute__((address_space(3))) unsigned int*)l, 16, 0, 0);
}

// chunking: q-block Q (QBLK=128) has 2Q+2 tiles of 64; nc = ceil((2Q+2)/16)
__device__ __forceinline__ int ncq(int Q){
  return Q < 8 ? 1 : 2;
}

// ---------------- all f32->bf16 conversions in ONE launch ----------------
// blocks [0,6144): x (MROWS*CDIM); blocks [6144,8448): 4 weights (576 each)
__global__ __launch_bounds__(256) void cvt_all(
    const float* __restrict__ x,
    const float* __restrict__ w0, const float* __restrict__ w1,
    const float* __restrict__ w2, const float* __restrict__ w3,
    unsigned short* __restrict__ xb, unsigned short* __restrict__ wout){
  const int bid = blockIdx.x;
  const float* src;
  unsigned short* dst;
  int i;
  if (bid < 6144){
    src = x; dst = xb;
    i = bid * 256 + threadIdx.x;
  } else {
    const int wb = bid - 6144;
    const int which = wb / 576;
    src = which == 0 ? w0 : which == 1 ? w1 : which == 2 ? w2 : w3;
    dst = wout + (size_t)which * CDIM * CDIM;
    i = (wb % 576) * 256 + threadIdx.x;
  }
  float4 v = reinterpret_cast<const float4*>(src)[i];
  ushort4 o;
  o.x = f2bf(v.x); o.y = f2bf(v.y); o.z = f2bf(v.z); o.w = f2bf(v.w);
  reinterpret_cast<ushort4*>(dst)[i] = o;
}

// ---------------- GEMM: C = A(MxK,bf16) * B(NxK,bf16)^T ----------------
// 128x128 tile, BK=64, global_load_lds(16B) into linear LDS, XOR slot-swizzle
// both-sides. Waves own 32 ROWS x 128 cols (acc[2][8]); EPI=1 fuses
// RoPE+RMSNorm for q/k col-tiles of QKV (Q additionally pre-scaled by
// 1/sqrt(128)*log2e so attention softmax runs in exp2 domain) and
// TRANSPOSES V col-tiles into Vt via LDS bounce.
template<int EPI>
__global__ __launch_bounds__(256) void gemm_bt(
    const unsigned short* __restrict__ A,
    const unsigned short* __restrict__ B,
    void* __restrict__ Cv, int M, int N, int K,
    const float* __restrict__ cosp, const float* __restrict__ sinp,
    unsigned short* __restrict__ Vt)
{
  __shared__ unsigned short sh[128 * 128];  // As = sh[0:8192), Bs = sh[8192:)
  unsigned short* As = sh;
  unsigned short* Bs = sh + 128 * 64;
  const int tid  = threadIdx.x;
  const int lane = tid & 63;
  const int wave = tid >> 6;
  const int lr = lane & 15, lg = lane >> 4;
  const int srow = lane >> 3;               // staging row within 8-row seg
  const int sslot = (lane & 7) ^ (lane >> 3);  // pre-swizzled global slot
  // XCD-aware swizzle; within an XCD, col-tiles vary fastest (A-panel reuse)
  const int gx = gridDim.x, gy = gridDim.y, nwg = gx * gy;
  const int flat = blockIdx.y * gx + blockIdx.x;
  const int nf = (flat & 7) * (nwg >> 3) + (flat >> 3);
  const int row0 = (nf / gy) * 128, col0 = (nf % gy) * 128;
  const int wrow = wave * 32;               // wave's row base within tile

  f32x4 acc[2][8];
  const f32x4 z = {0.f, 0.f, 0.f, 0.f};
  #pragma unroll
  for (int i = 0; i < 2; ++i)
    #pragma unroll
    for (int j = 0; j < 8; ++j) acc[i][j] = z;

  for (int k0 = 0; k0 < K; k0 += 64){
    #pragma unroll
    for (int i = 0; i < 4; ++i){
      int seg = wave * 4 + i;                 // 8 rows per 1KB segment
      int r = seg * 8 + srow;
      gload_lds16(&A[(size_t)(row0 + r) * K + k0 + sslot * 8], &As[seg * 512]);
      gload_lds16(&B[(size_t)(col0 + r) * K + k0 + sslot * 8], &Bs[seg * 512]);
    }
    __syncthreads();
    #pragma unroll
    for (int kk = 0; kk < 64; kk += 32){
      bf16x8 af[2], bfr[8];
      #pragma unroll
      for (int mi = 0; mi < 2; ++mi)
        af[mi] = *reinterpret_cast<const bf16x8*>(
            &As[(wrow + mi*16 + lr) * 64 + ((((kk>>3) + lg) ^ (lr & 7)) * 8)]);
      #pragma unroll
      for (int ni = 0; ni < 8; ++ni)
        bfr[ni] = *reinterpret_cast<const bf16x8*>(
            &Bs[(ni*16 + lr) * 64 + ((((kk>>3) + lg) ^ (lr & 7)) * 8)]);
      #pragma unroll
      for (int mi = 0; mi < 2; ++mi)
        #pragma unroll
        for (int ni = 0; ni < 8; ++ni)
          acc[mi][ni] = __builtin_amdgcn_mfma_f32_16x16x32_bf16(af[mi], bfr[ni], acc[mi][ni], 0, 0, 0);
    }
    __syncthreads();
  }

  if (EPI == 0){
    float* Cf = reinterpret_cast<float*>(Cv);
    #pragma unroll
    for (int mi = 0; mi < 2; ++mi)
      #pragma unroll
      for (int ni = 0; ni < 8; ++ni)
        #pragma unroll
        for (int r = 0; r < 4; ++r)
          Cf[(size_t)(row0 + wrow + mi*16 + lg*4 + r) * N + col0 + ni*16 + lr] = acc[mi][ni][r];
  } else {
    unsigned short* Cb = reinterpret_cast<unsigned short*>(Cv);
    const int ct = col0 >> 7;               // 0..17
    if (ct >= 12){
      // V tile: transpose via LDS bounce -> Vt[(b,h)][d][t]
      const int hh = ct - 12;
      const int b2 = row0 >> 11, t0 = row0 & (T_SEQ - 1);
      #pragma unroll
      for (int mi = 0; mi < 2; ++mi)
        #pragma unroll
        for (int ni = 0; ni < 8; ++ni)
          #pragma unroll
          for (int r = 0; r < 4; ++r){
            const int trow = wrow + mi*16 + lg*4 + r;
            const int col  = ni*16 + lr;
            sh[trow * 128 + (col ^ ((trow & 7) << 4))] = f2bf(acc[mi][ni][r]);
          }
      __syncthreads();
      const int dd = tid >> 1, tq = (tid & 1) * 64;
      unsigned short* dst =
          Vt + ((size_t)(b2 * NH + hh) * HD + dd) * T_SEQ + t0 + tq;
      #pragma unroll
      for (int j8 = 0; j8 < 8; ++j8){
        union { int4 v; unsigned short u[8]; } w;
        #pragma unroll
        for (int jj = 0; jj < 8; ++jj){
          const int tt = tq + j8 * 8 + jj;     // (tt & 7) == jj
          w.u[jj] = sh[tt * 128 + (dd ^ (jj << 4))];
        }
        *reinterpret_cast<int4*>(&dst[j8 * 8]) = w.v;
      }
    } else {
      // Q or K: RoPE (pairs d, d+64 = ni, ni+4) + RMSNorm over 128, then bf16
      // Q tiles (ct<6) additionally scaled by QSCL (softmax exp2-domain)
      const float post = (ct < 6) ? QSCL : 1.0f;
      #pragma unroll
      for (int mi = 0; mi < 2; ++mi){
        #pragma unroll
        for (int r = 0; r < 4; ++r){
          const int row = row0 + wrow + mi*16 + lg*4 + r;
          const int t = row & (T_SEQ - 1);
          float y1[4], y2[4], ssp = 0.f;
          #pragma unroll
          for (int ni = 0; ni < 4; ++ni){
            const int d = ni*16 + lr;
            float c = cosp[t * 64 + d];
            float s = sinp[t * 64 + d];
            float x1 = acc[mi][ni][r], x2 = acc[mi][ni+4][r];
            y1[ni] = x1 * c + x2 * s;
            y2[ni] = x2 * c - x1 * s;
            ssp += y1[ni]*y1[ni] + y2[ni]*y2[ni];
          }
          #pragma unroll
          for (int off = 1; off < 16; off <<= 1) ssp += __shfl_xor(ssp, off);
          const float inv = rsqrtf(ssp * (1.0f / 128.0f) + 1e-15f) * post;
          #pragma unroll
          for (int ni = 0; ni < 4; ++ni){
            const int d = ni*16 + lr;
            Cb[(size_t)row * N + col0 + d]      = f2bf(y1[ni] * inv);
            Cb[(size_t)row * N + col0 + d + 64] = f2bf(y2[ni] * inv);
          }
        }
      }
    }
  }
}

// ---------------- causal flash attention: 32x32 swapped-operand, 128-kv super-tiles ----------------
// 4 waves x 32 q-rows (QBLK=128), chunks of <=16 kv-tiles -> 576 blocks as in
// round 22, but KV is staged in 128-row SUPER-TILES: one barrier pair + one
// vmcnt drain per 128 kv (was per 64). The two 64-kv sub-tiles are computed
// back-to-back inside the barrier window. Chunk halves split at even 64-tile
// boundaries so every chunk pairs cleanly. Dynamic LDS 69632B (2 blocks/CU).
__global__ __launch_bounds__(256) void attn_fwd(
    const unsigned short* __restrict__ QKVb,   // rope'd Q,K in place
    const unsigned short* __restrict__ Vt,     // (B*H, D, T)
    unsigned short* __restrict__ AO,
    unsigned short* __restrict__ Op, float* __restrict__ Mp, float* __restrict__ Lp)
{
  extern __shared__ unsigned short shm[];
  unsigned short* Ks = shm;                 // [128][136] bf16 (34816 B)
  unsigned short* Vs = shm + 128 * 136;     // [128 d][136 kv-pitch] (34816 B)
  const int tid = threadIdx.x;
  const int lane = tid & 63, wave = tid >> 6;
  const int l31 = lane & 31, hi = lane >> 5;

  // XCD-aware remap: 576 blocks, 72/XCD = 3 heads' 24 chunks each
  const int flat = blockIdx.x;
  const int nf = (flat & 7) * 72 + (flat >> 3);
  const int bh = nf / 24;
  const int L = 23 - (nf % 24);              // big chunks first within XCD
  int Q, c;
  if (L < 8){ Q = L; c = 0; }
  else      { int m = L - 8; Q = 8 + (m >> 1); c = m & 1; }
  const int nc = ncq(Q);
  const int tiles = 2 * Q + 2;               // always even
  int tbeg, tend;
  if (nc == 1){ tbeg = 0; tend = tiles; }
  else {
    const int half0 = ((Q + 2) >> 1) << 1;   // even split point
    tbeg = c ? half0 : 0;
    tend = c ? tiles : half0;
  }
  const int b = bh / NH, h = bh % NH;
  const int qw = Q * 128 + wave * 32;

  const unsigned short* Qp = QKVb + (size_t)(b * T_SEQ) * NQKV + h * HD;
  const unsigned short* Kp = QKVb + (size_t)(b * T_SEQ) * NQKV + CDIM + h * HD;
  const unsigned short* Vp = Vt + (size_t)bh * HD * T_SEQ;

  // staging coords: K 128 rows x 16 col-chunks; V 128 d-rows x 16 kv-chunks
  const int kr = tid >> 4, kc4 = (tid & 15) * 8;    // K row base, col chunk
  const int vr = tid >> 3, vc4 = (tid & 7) * 8;     // V d-row base, kv chunk

  // Q B-frags: B[k=8hi+j][n=l31] = Q[q=qw+l31][d=16c4+8hi+j]
  bf16x8 qf[8];
  #pragma unroll
  for (int c4 = 0; c4 < 8; ++c4)
    qf[c4] = *reinterpret_cast<const bf16x8*>(
        &Qp[(size_t)(qw + l31) * NQKV + c4 * 16 + hi * 8]);

  f32x16 o[4];
  #pragma unroll
  for (int db = 0; db < 4; ++db)
    #pragma unroll
    for (int r = 0; r < 16; ++r) o[db][r] = 0.f;
  float mrun = -__builtin_inff(), lrun = 0.f;   // mrun in log2 domain

  // staging registers for one 128-kv super-tile
  int4 gk0, gk1, gk2, gk3, gk4, gk5, gk6, gk7;
  int4 gv0, gv1, gv2, gv3, gv4, gv5, gv6, gv7;

#define LOADST(KV0)                                                            \
  { const int _k = (KV0);                                                      \
    gk0 = *reinterpret_cast<const int4*>(&Kp[(size_t)(_k + kr)        * NQKV + kc4]); \
    gk1 = *reinterpret_cast<const int4*>(&Kp[(size_t)(_k + kr + 16)   * NQKV + kc4]); \
    gk2 = *reinterpret_cast<const int4*>(&Kp[(size_t)(_k + kr + 32)   * NQKV + kc4]); \
    gk3 = *reinterpret_cast<const int4*>(&Kp[(size_t)(_k + kr + 48)   * NQKV + kc4]); \
    gk4 = *reinterpret_cast<const int4*>(&Kp[(size_t)(_k + kr + 64)   * NQKV + kc4]); \
    gk5 = *reinterpret_cast<const int4*>(&Kp[(size_t)(_k + kr + 80)   * NQKV + kc4]); \
    gk6 = *reinterpret_cast<const int4*>(&Kp[(size_t)(_k + kr + 96)   * NQKV + kc4]); \
    gk7 = *reinterpret_cast<const int4*>(&Kp[(size_t)(_k + kr + 112)  * NQKV + kc4]); \
    gv0 = *reinterpret_cast<const int4*>(&Vp[(size_t)(vr)       * T_SEQ + _k + vc4]);      \
    gv1 = *reinterpret_cast<const int4*>(&Vp[(size_t)(vr + 32)  * T_SEQ + _k + vc4]);      \
    gv2 = *reinterpret_cast<const int4*>(&Vp[(size_t)(vr + 64)  * T_SEQ + _k + vc4]);      \
    gv3 = *reinterpret_cast<const int4*>(&Vp[(size_t)(vr + 96)  * T_SEQ + _k + vc4]);      \
    gv4 = *reinterpret_cast<const int4*>(&Vp[(size_t)(vr)       * T_SEQ + _k + 64 + vc4]); \
    gv5 = *reinterpret_cast<const int4*>(&Vp[(size_t)(vr + 32)  * T_SEQ + _k + 64 + vc4]); \
    gv6 = *reinterpret_cast<const int4*>(&Vp[(size_t)(vr + 64)  * T_SEQ + _k + 64 + vc4]); \
    gv7 = *reinterpret_cast<const int4*>(&Vp[(size_t)(vr + 96)  * T_SEQ + _k + 64 + vc4]); }

  // prologue: load super-tile tbeg into registers
  LOADST(tbeg * 64);

  for (int t = tbeg; t < tend; t += 2){
    // ---- ds_write super-tile from registers (vmcnt wait auto-inserted) ----
    *reinterpret_cast<int4*>(&Ks[(kr)       * 136 + kc4]) = gk0;
    *reinterpret_cast<int4*>(&Ks[(kr + 16)  * 136 + kc4]) = gk1;
    *reinterpret_cast<int4*>(&Ks[(kr + 32)  * 136 + kc4]) = gk2;
    *reinterpret_cast<int4*>(&Ks[(kr + 48)  * 136 + kc4]) = gk3;
    *reinterpret_cast<int4*>(&Ks[(kr + 64)  * 136 + kc4]) = gk4;
    *reinterpret_cast<int4*>(&Ks[(kr + 80)  * 136 + kc4]) = gk5;
    *reinterpret_cast<int4*>(&Ks[(kr + 96)  * 136 + kc4]) = gk6;
    *reinterpret_cast<int4*>(&Ks[(kr + 112) * 136 + kc4]) = gk7;
    *reinterpret_cast<int4*>(&Vs[(vr)      * 136 + vc4])      = gv0;
    *reinterpret_cast<int4*>(&Vs[(vr + 32) * 136 + vc4])      = gv1;
    *reinterpret_cast<int4*>(&Vs[(vr + 64) * 136 + vc4])      = gv2;
    *reinterpret_cast<int4*>(&Vs[(vr + 96) * 136 + vc4])      = gv3;
    *reinterpret_cast<int4*>(&Vs[(vr)      * 136 + 64 + vc4]) = gv4;
    *reinterpret_cast<int4*>(&Vs[(vr + 32) * 136 + 64 + vc4]) = gv5;
    *reinterpret_cast<int4*>(&Vs[(vr + 64) * 136 + 64 + vc4]) = gv6;
    *reinterpret_cast<int4*>(&Vs[(vr + 96) * 136 + 64 + vc4]) = gv7;
    __syncthreads();

    // ---- issue next super-tile loads (latency hides under compute) ----
    if (t + 2 < tend) LOADST((t + 2) * 64);

    // ---- two 64-kv sub-tiles inside one barrier window ----
    #pragma unroll
    for (int sub = 0; sub < 2; ++sub){
      const int kv0 = (t + sub) * 64;
      if (kv0 > qw + 31) break;              // masked-out for this wave
      const int rb = sub * 64;               // LDS row/col base of sub-tile

      // ---- S^T = K Q^T (Q pre-scaled): lane holds S[kv][q=qw+l31] ----
      f32x16 s[2];
      #pragma unroll
      for (int r = 0; r < 16; ++r){ s[0][r] = 0.f; s[1][r] = 0.f; }
      __builtin_amdgcn_s_setprio(1);
      #pragma unroll
      for (int c4 = 0; c4 < 8; ++c4){
        bf16x8 k0 = *reinterpret_cast<const bf16x8*>(
            &Ks[(rb + l31) * 136 + c4 * 16 + hi * 8]);
        bf16x8 k1 = *reinterpret_cast<const bf16x8*>(
            &Ks[(rb + 32 + l31) * 136 + c4 * 16 + hi * 8]);
        s[0] = __builtin_amdgcn_mfma_f32_32x32x16_bf16(k0, qf[c4], s[0], 0, 0, 0);
        s[1] = __builtin_amdgcn_mfma_f32_32x32x16_bf16(k1, qf[c4], s[1], 0, 0, 0);
      }
      __builtin_amdgcn_s_setprio(0);

      // ---- causal mask (diagonal tiles only; interior: no scale work) ----
      const int qg = qw + l31;
      if (kv0 + 63 > qw){
        #pragma unroll
        for (int blk = 0; blk < 2; ++blk)
          #pragma unroll
          for (int r = 0; r < 16; ++r){
            int kg = kv0 + 32 * blk + (r & 3) + 8 * (r >> 2) + 4 * hi;
            s[blk][r] = (kg <= qg) ? s[blk][r] : -__builtin_inff();
          }
      }

      // ---- row max: tree over own 32 + 1 cross-half shuffle ----
      float t8[8];
      #pragma unroll
      for (int blk = 0; blk < 2; ++blk)
        #pragma unroll
        for (int j = 0; j < 4; ++j)
          t8[blk * 4 + j] = fmaxf(fmaxf(s[blk][4*j], s[blk][4*j+1]),
                                  fmaxf(s[blk][4*j+2], s[blk][4*j+3]));
      float pm = fmaxf(fmaxf(fmaxf(t8[0], t8[1]), fmaxf(t8[2], t8[3])),
                       fmaxf(fmaxf(t8[4], t8[5]), fmaxf(t8[6], t8[7])));
      pm = fmaxf(pm, __shfl_xor(pm, 32));

      // ---- deferred rescale (wave-uniform; exp2 domain, raw v_exp) ----
      if (__any(pm > mrun)){
        float mn = fmaxf(mrun, pm);
        float scf = (mrun == -__builtin_inff()) ? 0.f : ex2(mrun - mn);
        mrun = mn; lrun *= scf;
        #pragma unroll
        for (int r = 0; r < 16; ++r){
          float scr = __shfl(scf, (r & 3) + 8 * (r >> 2) + 4 * hi, 32);
          #pragma unroll
          for (int db = 0; db < 4; ++db) o[db][r] *= scr;
        }
      }

      // ---- exp2 (raw v_exp_f32) + row sum ----
      float a8[8];
      #pragma unroll
      for (int blk = 0; blk < 2; ++blk)
        #pragma unroll
        for (int j = 0; j < 4; ++j){
          float p0 = ex2(s[blk][4*j]   - mrun);
          float p1 = ex2(s[blk][4*j+1] - mrun);
          float p2 = ex2(s[blk][4*j+2] - mrun);
          float p3 = ex2(s[blk][4*j+3] - mrun);
          s[blk][4*j] = p0; s[blk][4*j+1] = p1; s[blk][4*j+2] = p2; s[blk][4*j+3] = p3;
          a8[blk * 4 + j] = (p0 + p1) + (p2 + p3);
        }
      float ls = ((a8[0] + a8[1]) + (a8[2] + a8[3])) + ((a8[4] + a8[5]) + (a8[6] + a8[7]));
      lrun += ls + __shfl_xor(ls, 32);

      // ---- O += P V : A-frags via cvt_pk + permlane32_swap ----
      __builtin_amdgcn_s_setprio(1);
      #pragma unroll
      for (int kc = 0; kc < 4; ++kc){
        const int blk = kc >> 1, base2 = (kc & 1) * 8;
        unsigned int a0 = cvtpk(s[blk][base2+0], s[blk][base2+1]);
        unsigned int b0 = cvtpk(s[blk][base2+4], s[blk][base2+5]);
        unsigned int a1 = cvtpk(s[blk][base2+2], s[blk][base2+3]);
        unsigned int b1 = cvtpk(s[blk][base2+6], s[blk][base2+7]);
        i32x2 sw0 = __builtin_amdgcn_permlane32_swap((int)a0, (int)b0, false, false);
        i32x2 sw1 = __builtin_amdgcn_permlane32_swap((int)a1, (int)b1, false, false);
        union { bf16x8 v; unsigned int u[4]; } pa;
        pa.u[0] = (unsigned int)sw0[0];   // kv 8hi+{0,1}
        pa.u[1] = (unsigned int)sw1[0];   // kv 8hi+{2,3}
        pa.u[2] = (unsigned int)sw0[1];   // kv 8hi+{4,5}
        pa.u[3] = (unsigned int)sw1[1];   // kv 8hi+{6,7}
        #pragma unroll
        for (int db = 0; db < 4; ++db){
          bf16x8 vf = *reinterpret_cast<const bf16x8*>(
              &Vs[(db * 32 + l31) * 136 + rb + kc * 16 + hi * 8]);
          o[db] = __builtin_amdgcn_mfma_f32_32x32x16_bf16(pa.v, vf, o[db], 0, 0, 0);
        }
      }
      __builtin_amdgcn_s_setprio(0);
    }
    __syncthreads();   // Ks/Vs free for next super-tile's ds_writes
  }

  if (nc == 1){
    // ---- final (Q<8): O /= l; write AO in (B,T,C) bf16 ----
    float inv = 1.0f / lrun;                 // this lane's q = qw + l31
    #pragma unroll
    for (int r = 0; r < 16; ++r){
      const int crow = (r & 3) + 8 * (r >> 2) + 4 * hi;
      float ir = __shfl(inv, crow, 32);
      #pragma unroll
      for (int db = 0; db < 4; ++db)
        AO[((size_t)b * T_SEQ + qw + crow) * CDIM + h * HD + db * 32 + l31] =
            f2bf(o[db][r] * ir);
    }
  } else {
    // ---- partial: unnormalized O (bf16) + m,l per row (m in log2 domain) ----
    const int slot = bh * 16 + 2 * (Q - 8) + c;
    unsigned short* OpW = Op + (size_t)slot * 128 * 128;
    #pragma unroll
    for (int r = 0; r < 16; ++r){
      const int row = wave * 32 + (r & 3) + 8 * (r >> 2) + 4 * hi;
      #pragma unroll
      for (int db = 0; db < 4; ++db)
        OpW[row * 128 + db * 32 + l31] = f2bf(o[db][r]);
    }
    if (hi == 0){
      Mp[(size_t)slot * 128 + wave * 32 + l31] = mrun;
      Lp[(size_t)slot * 128 + wave * 32 + l31] = lrun;
    }
  }
}

// ---------------- combine partials for q-blocks with nc==2 (Q=8..15) ----------------
__global__ __launch_bounds__(256) void attn_combine(
    const unsigned short* __restrict__ Op, const float* __restrict__ Mp,
    const float* __restrict__ Lp, unsigned short* __restrict__ AO)
{
  const int Q  = 8 + blockIdx.x;            // 8..15
  const int bh = blockIdx.y;
  const int b = bh / NH, h = bh % NH;
  const int slot0 = bh * 16 + 2 * (Q - 8);
  #pragma unroll
  for (int u = 0; u < 16; ++u){
    int unit = threadIdx.x + u * 256;       // 128 rows x 32 4-col groups
    int r = unit >> 5, d4 = unit & 31;
    const float m0 = Mp[(size_t)slot0 * 128 + r];
    const float m1 = Mp[(size_t)(slot0 + 1) * 128 + r];
    const float m = fmaxf(m0, m1);
    const float w0 = __builtin_amdgcn_exp2f(m0 - m);
    const float w1 = __builtin_amdgcn_exp2f(m1 - m);
    const float l = w0 * Lp[(size_t)slot0 * 128 + r]
                  + w1 * Lp[(size_t)(slot0 + 1) * 128 + r];
    const ushort4 v0 = *reinterpret_cast<const ushort4*>(
        &Op[((size_t)slot0 * 128 + r) * 128 + d4 * 4]);
    const ushort4 v1 = *reinterpret_cast<const ushort4*>(
        &Op[((size_t)(slot0 + 1) * 128 + r) * 128 + d4 * 4]);
    const float inv = 1.0f / l;
    ushort4 ov;
    ov.x = f2bf((w0 * bf2f(v0.x) + w1 * bf2f(v1.x)) * inv);
    ov.y = f2bf((w0 * bf2f(v0.y) + w1 * bf2f(v1.y)) * inv);
    ov.z = f2bf((w0 * bf2f(v0.z) + w1 * bf2f(v1.z)) * inv);
    ov.w = f2bf((w0 * bf2f(v0.w) + w1 * bf2f(v1.w)) * inv);
    *reinterpret_cast<ushort4*>(
        &AO[((size_t)b * T_SEQ + Q * 128 + r) * CDIM + h * HD + d4 * 4]) = ov;
  }
}

// ---------------- launch ----------------
extern "C" void kernel_launch(void* const* d_in, const int* in_sizes, int n_in,
                              void* d_out, int out_size, void* d_ws, size_t ws_size,
                              hipStream_t stream)
{
  (void)in_sizes; (void)n_in; (void)out_size; (void)ws_size;
  const float* x    = (const float*)d_in[0];
  const float* cosp = (const float*)d_in[1];
  const float* sinp = (const float*)d_in[2];
  const float* Wq   = (const float*)d_in[3];
  const float* Wk   = (const float*)d_in[4];
  const float* Wv   = (const float*)d_in[5];
  const float* Wo   = (const float*)d_in[6];
  float* out = (float*)d_out;

  // workspace layout: bf16 region then partials (~95 MB)
  unsigned short* xb    = (unsigned short*)d_ws;
  unsigned short* Wqkvb = xb    + (size_t)MROWS * CDIM;
  unsigned short* Wob   = Wqkvb + (size_t)NQKV * CDIM;
  unsigned short* QKVb  = Wob   + (size_t)CDIM * CDIM;
  unsigned short* Vtb   = QKVb  + (size_t)MROWS * NQKV;
  unsigned short* AO    = Vtb   + (size_t)MROWS * CDIM;
  unsigned short* Op    = AO    + (size_t)MROWS * CDIM;
  float* Mp = (float*)(Op + (size_t)NSLOT * 128 * 128);
  float* Lp = Mp + (size_t)NSLOT * 128;

  // opt in to >64KB dynamic LDS for the super-tile attention kernel
  (void)hipFuncSetAttribute((const void*)attn_fwd,
                            hipFuncAttributeMaxDynamicSharedMemorySize, 69632);

  // all f32->bf16 conversions in one launch (x + 4 weight matrices)
  cvt_all<<<8448, 256, 0, stream>>>(x, Wq, Wk, Wv, Wo, xb, Wqkvb);

  // fused QKV projection + RoPE/RMSNorm(+Q-prescale) + V-transpose epilogue
  gemm_bt<1><<<dim3(MROWS / 128, NQKV / 128), 256, 0, stream>>>(
      xb, Wqkvb, QKVb, MROWS, NQKV, CDIM, cosp, sinp, Vtb);
  // causal flash attention, 128-kv super-tiles -> AO (+partials)
  attn_fwd<<<576, 256, 69632, stream>>>(QKVb, Vtb, AO, Op, Mp, Lp);
  attn_combine<<<dim3(8, 24), 256, 0, stream>>>(Op, Mp, Lp, AO);
  // output projection -> f32 d_out
  gemm_bt<0><<<dim3(MROWS / 128, CDIM / 128), 256, 0, stream>>>(
      AO, Wob, out, MROWS, CDIM, CDIM, nullptr, nullptr, nullptr);
}

// Round 24
// 177.018 us; speedup vs baseline: 1.0014x; 1.0014x over previous
//
#include <hip/hip_runtime.h>

#define T_SEQ 2048
#define NH    6
#define HD    128
#define CDIM  768
#define NQKV  2304
#define MROWS 8192   // B*T = 4*2048
#define NSLOT 384    // 16 partial chunks per (b,h) * 24
// 1/sqrt(128) * log2(e): folded into Q during gemm1 epilogue
#define QSCL  0.12754011021989615f

typedef __attribute__((ext_vector_type(8)))  short bf16x8;
typedef __attribute__((ext_vector_type(4)))  float f32x4;
typedef __attribute__((ext_vector_type(16))) float f32x16;
typedef __attribute__((ext_vector_type(2)))  int   i32x2;

__device__ __forceinline__ unsigned short f2bf(float f){
  unsigned int u = __builtin_bit_cast(unsigned int, f);
  u += 0x7fffu + ((u >> 16) & 1u);          // round-to-nearest-even
  return (unsigned short)(u >> 16);
}
__device__ __forceinline__ float bf2f(unsigned short h){
  unsigned int u = ((unsigned int)h) << 16;
  return __builtin_bit_cast(float, u);
}
// raw v_exp_f32: computes 2^x in one instruction (no libm slow path)
__device__ __forceinline__ float ex2(float x){
  return __builtin_amdgcn_exp2f(x);
}
// pack 2 f32 -> 2 bf16 in one instr
__device__ __forceinline__ unsigned int cvtpk(float lo, float hi){
  unsigned int r;
  asm("v_cvt_pk_bf16_f32 %0, %1, %2" : "=v"(r) : "v"(lo), "v"(hi));
  return r;
}

// async global->LDS, 16B per lane; LDS dest is wave-uniform base + lane*16
__device__ __forceinline__ void gload_lds16(const void* g, void* l){
  __builtin_amdgcn_global_load_lds(
      (const __attribute__((address_space(1))) unsigned int*)g,
      (__attribute__((address_space(3))) unsigned int*)l, 16, 0, 0);
}

// chunking: q-block Q (QBLK=128) has 2Q+2 tiles of 64; nc = ceil((2Q+2)/16)
__device__ __forceinline__ int ncq(int Q){
  return Q < 8 ? 1 : 2;
}
// chunks before q-block Q (total 24 per bh)
__device__ __forceinline__ int cumc(int Q){
  return Q < 8 ? Q : 8 + 2*(Q-8);
}

// ---------------- all f32->bf16 conversions in ONE launch ----------------
// blocks [0,6144): x (MROWS*CDIM); blocks [6144,8448): 4 weights (576 each)
__global__ __launch_bounds__(256) void cvt_all(
    const float* __restrict__ x,
    const float* __restrict__ w0, const float* __restrict__ w1,
    const float* __restrict__ w2, const float* __restrict__ w3,
    unsigned short* __restrict__ xb, unsigned short* __restrict__ wout){
  const int bid = blockIdx.x;
  const float* src;
  unsigned short* dst;
  int i;
  if (bid < 6144){
    src = x; dst = xb;
    i = bid * 256 + threadIdx.x;
  } else {
    const int wb = bid - 6144;
    const int which = wb / 576;
    src = which == 0 ? w0 : which == 1 ? w1 : which == 2 ? w2 : w3;
    dst = wout + (size_t)which * CDIM * CDIM;
    i = (wb % 576) * 256 + threadIdx.x;
  }
  float4 v = reinterpret_cast<const float4*>(src)[i];
  ushort4 o;
  o.x = f2bf(v.x); o.y = f2bf(v.y); o.z = f2bf(v.z); o.w = f2bf(v.w);
  reinterpret_cast<ushort4*>(dst)[i] = o;
}

// ---------------- GEMM: C = A(MxK,bf16) * B(NxK,bf16)^T ----------------
// 128x128 tile, BK=64, global_load_lds(16B) into linear LDS, XOR slot-swizzle
// both-sides. Waves own 32 ROWS x 128 cols (acc[2][8]); EPI=1 fuses
// RoPE+RMSNorm for q/k col-tiles of QKV (Q additionally pre-scaled by
// 1/sqrt(128)*log2e so attention softmax runs in exp2 domain) and
// TRANSPOSES V col-tiles into Vt via LDS bounce.
template<int EPI>
__global__ __launch_bounds__(256) void gemm_bt(
    const unsigned short* __restrict__ A,
    const unsigned short* __restrict__ B,
    void* __restrict__ Cv, int M, int N, int K,
    const float* __restrict__ cosp, const float* __restrict__ sinp,
    unsigned short* __restrict__ Vt)
{
  __shared__ unsigned short sh[128 * 128];  // As = sh[0:8192), Bs = sh[8192:)
  unsigned short* As = sh;
  unsigned short* Bs = sh + 128 * 64;
  const int tid  = threadIdx.x;
  const int lane = tid & 63;
  const int wave = tid >> 6;
  const int lr = lane & 15, lg = lane >> 4;
  const int srow = lane >> 3;               // staging row within 8-row seg
  const int sslot = (lane & 7) ^ (lane >> 3);  // pre-swizzled global slot
  // XCD-aware swizzle; within an XCD, col-tiles vary fastest (A-panel reuse)
  const int gx = gridDim.x, gy = gridDim.y, nwg = gx * gy;
  const int flat = blockIdx.y * gx + blockIdx.x;
  const int nf = (flat & 7) * (nwg >> 3) + (flat >> 3);
  const int row0 = (nf / gy) * 128, col0 = (nf % gy) * 128;
  const int wrow = wave * 32;               // wave's row base within tile

  f32x4 acc[2][8];
  const f32x4 z = {0.f, 0.f, 0.f, 0.f};
  #pragma unroll
  for (int i = 0; i < 2; ++i)
    #pragma unroll
    for (int j = 0; j < 8; ++j) acc[i][j] = z;

  for (int k0 = 0; k0 < K; k0 += 64){
    #pragma unroll
    for (int i = 0; i < 4; ++i){
      int seg = wave * 4 + i;                 // 8 rows per 1KB segment
      int r = seg * 8 + srow;
      gload_lds16(&A[(size_t)(row0 + r) * K + k0 + sslot * 8], &As[seg * 512]);
      gload_lds16(&B[(size_t)(col0 + r) * K + k0 + sslot * 8], &Bs[seg * 512]);
    }
    __syncthreads();
    #pragma unroll
    for (int kk = 0; kk < 64; kk += 32){
      bf16x8 af[2], bfr[8];
      #pragma unroll
      for (int mi = 0; mi < 2; ++mi)
        af[mi] = *reinterpret_cast<const bf16x8*>(
            &As[(wrow + mi*16 + lr) * 64 + ((((kk>>3) + lg) ^ (lr & 7)) * 8)]);
      #pragma unroll
      for (int ni = 0; ni < 8; ++ni)
        bfr[ni] = *reinterpret_cast<const bf16x8*>(
            &Bs[(ni*16 + lr) * 64 + ((((kk>>3) + lg) ^ (lr & 7)) * 8)]);
      #pragma unroll
      for (int mi = 0; mi < 2; ++mi)
        #pragma unroll
        for (int ni = 0; ni < 8; ++ni)
          acc[mi][ni] = __builtin_amdgcn_mfma_f32_16x16x32_bf16(af[mi], bfr[ni], acc[mi][ni], 0, 0, 0);
    }
    __syncthreads();
  }

  if (EPI == 0){
    float* Cf = reinterpret_cast<float*>(Cv);
    #pragma unroll
    for (int mi = 0; mi < 2; ++mi)
      #pragma unroll
      for (int ni = 0; ni < 8; ++ni)
        #pragma unroll
        for (int r = 0; r < 4; ++r)
          Cf[(size_t)(row0 + wrow + mi*16 + lg*4 + r) * N + col0 + ni*16 + lr] = acc[mi][ni][r];
  } else {
    unsigned short* Cb = reinterpret_cast<unsigned short*>(Cv);
    const int ct = col0 >> 7;               // 0..17
    if (ct >= 12){
      // V tile: transpose via LDS bounce -> Vt[(b,h)][d][t]
      const int hh = ct - 12;
      const int b2 = row0 >> 11, t0 = row0 & (T_SEQ - 1);
      #pragma unroll
      for (int mi = 0; mi < 2; ++mi)
        #pragma unroll
        for (int ni = 0; ni < 8; ++ni)
          #pragma unroll
          for (int r = 0; r < 4; ++r){
            const int trow = wrow + mi*16 + lg*4 + r;
            const int col  = ni*16 + lr;
            sh[trow * 128 + (col ^ ((trow & 7) << 4))] = f2bf(acc[mi][ni][r]);
          }
      __syncthreads();
      const int dd = tid >> 1, tq = (tid & 1) * 64;
      unsigned short* dst =
          Vt + ((size_t)(b2 * NH + hh) * HD + dd) * T_SEQ + t0 + tq;
      #pragma unroll
      for (int j8 = 0; j8 < 8; ++j8){
        union { int4 v; unsigned short u[8]; } w;
        #pragma unroll
        for (int jj = 0; jj < 8; ++jj){
          const int tt = tq + j8 * 8 + jj;     // (tt & 7) == jj
          w.u[jj] = sh[tt * 128 + (dd ^ (jj << 4))];
        }
        *reinterpret_cast<int4*>(&dst[j8 * 8]) = w.v;
      }
    } else {
      // Q or K: RoPE (pairs d, d+64 = ni, ni+4) + RMSNorm over 128, then bf16
      // Q tiles (ct<6) additionally scaled by QSCL (softmax exp2-domain)
      const float post = (ct < 6) ? QSCL : 1.0f;
      #pragma unroll
      for (int mi = 0; mi < 2; ++mi){
        #pragma unroll
        for (int r = 0; r < 4; ++r){
          const int row = row0 + wrow + mi*16 + lg*4 + r;
          const int t = row & (T_SEQ - 1);
          float y1[4], y2[4], ssp = 0.f;
          #pragma unroll
          for (int ni = 0; ni < 4; ++ni){
            const int d = ni*16 + lr;
            float c = cosp[t * 64 + d];
            float s = sinp[t * 64 + d];
            float x1 = acc[mi][ni][r], x2 = acc[mi][ni+4][r];
            y1[ni] = x1 * c + x2 * s;
            y2[ni] = x2 * c - x1 * s;
            ssp += y1[ni]*y1[ni] + y2[ni]*y2[ni];
          }
          #pragma unroll
          for (int off = 1; off < 16; off <<= 1) ssp += __shfl_xor(ssp, off);
          const float inv = rsqrtf(ssp * (1.0f / 128.0f) + 1e-15f) * post;
          #pragma unroll
          for (int ni = 0; ni < 4; ++ni){
            const int d = ni*16 + lr;
            Cb[(size_t)row * N + col0 + d]      = f2bf(y1[ni] * inv);
            Cb[(size_t)row * N + col0 + d + 64] = f2bf(y2[ni] * inv);
          }
        }
      }
    }
  }
}

// ---------------- causal flash attention: 32x32 swapped-operand, big-chunk split-KV ----------------
// 4 waves x 32 q-rows (QBLK=128), KVBLK=64, chunks of <=16 tiles -> 576 blocks
// (24 chunks/bh; only Q>=8 splits, always into 2 even halves).
// Q pre-scaled by 1/sqrt(128)*log2e -> softmax in exp2 domain via RAW
// v_exp_f32. T14 async-STAGE split staging. XCD-local heads (3 per XCD).
__global__ __launch_bounds__(256) void attn_fwd(
    const unsigned short* __restrict__ QKVb,   // rope'd Q,K in place
    const unsigned short* __restrict__ Vt,     // (B*H, D, T)
    unsigned short* __restrict__ AO,
    unsigned short* __restrict__ Op, float* __restrict__ Mp, float* __restrict__ Lp)
{
  __shared__ unsigned short Ks[64][136];    // K tile [kv][d]
  __shared__ unsigned short Vs[128][72];    // V^T tile [d][kv]
  const int tid = threadIdx.x;
  const int lane = tid & 63, wave = tid >> 6;
  const int l31 = lane & 31, hi = lane >> 5;

  // XCD-aware remap: 576 blocks, 72/XCD = 3 heads' 24 chunks each
  const int flat = blockIdx.x;
  const int nf = (flat & 7) * 72 + (flat >> 3);
  const int bh = nf / 24;
  const int L = 23 - (nf % 24);              // big chunks first within XCD
  int Q, c;
  if (L < 8){ Q = L; c = 0; }
  else      { int m = L - 8; Q = 8 + (m >> 1); c = m & 1; }
  const int nc = ncq(Q);
  const int tiles = 2 * Q + 2;
  const int half = tiles >> 1;               // tiles always even
  const int tbeg = (nc == 1) ? 0    : c * half;
  const int tend = (nc == 1) ? tiles : tbeg + half;
  const int b = bh / NH, h = bh % NH;
  const int qw = Q * 128 + wave * 32;

  const unsigned short* Qp = QKVb + (size_t)(b * T_SEQ) * NQKV + h * HD;
  const unsigned short* Kp = QKVb + (size_t)(b * T_SEQ) * NQKV + CDIM + h * HD;
  const unsigned short* Vp = Vt + (size_t)bh * HD * T_SEQ;

  // staging coords (per thread): K: row kr (64 rows x 16 chunks), V: row vr
  const int kr = tid >> 4, kc4 = (tid & 15) * 8;    // K row, col chunk
  const int vr = tid >> 3, vc4 = (tid & 7) * 8;     // V d-row base

  // Q B-frags: B[k=8hi+j][n=l31] = Q[q=qw+l31][d=16c4+8hi+j]
  bf16x8 qf[8];
  #pragma unroll
  for (int c4 = 0; c4 < 8; ++c4)
    qf[c4] = *reinterpret_cast<const bf16x8*>(
        &Qp[(size_t)(qw + l31) * NQKV + c4 * 16 + hi * 8]);

  f32x16 o[4];
  #pragma unroll
  for (int db = 0; db < 4; ++db)
    #pragma unroll
    for (int r = 0; r < 16; ++r) o[db][r] = 0.f;
  float mrun = -__builtin_inff(), lrun = 0.f;   // mrun in log2 domain

  // prologue: load tile tbeg into registers
  int4 gk0, gk1, gk2, gk3, gv0, gv1, gv2, gv3;
  {
    const int kv0 = tbeg * 64;
    gk0 = *reinterpret_cast<const int4*>(&Kp[(size_t)(kv0 + kr)       * NQKV + kc4]);
    gk1 = *reinterpret_cast<const int4*>(&Kp[(size_t)(kv0 + kr + 16)  * NQKV + kc4]);
    gk2 = *reinterpret_cast<const int4*>(&Kp[(size_t)(kv0 + kr + 32)  * NQKV + kc4]);
    gk3 = *reinterpret_cast<const int4*>(&Kp[(size_t)(kv0 + kr + 48)  * NQKV + kc4]);
    gv0 = *reinterpret_cast<const int4*>(&Vp[(size_t)(vr)       * T_SEQ + kv0 + vc4]);
    gv1 = *reinterpret_cast<const int4*>(&Vp[(size_t)(vr + 32)  * T_SEQ + kv0 + vc4]);
    gv2 = *reinterpret_cast<const int4*>(&Vp[(size_t)(vr + 64)  * T_SEQ + kv0 + vc4]);
    gv3 = *reinterpret_cast<const int4*>(&Vp[(size_t)(vr + 96)  * T_SEQ + kv0 + vc4]);
  }

  for (int t = tbeg; t < tend; ++t){
    // ---- ds_write tile t from registers (vmcnt wait auto-inserted) ----
    *reinterpret_cast<int4*>(&Ks[kr][kc4])        = gk0;
    *reinterpret_cast<int4*>(&Ks[kr + 16][kc4])   = gk1;
    *reinterpret_cast<int4*>(&Ks[kr + 32][kc4])   = gk2;
    *reinterpret_cast<int4*>(&Ks[kr + 48][kc4])   = gk3;
    *reinterpret_cast<int4*>(&Vs[vr][vc4])        = gv0;
    *reinterpret_cast<int4*>(&Vs[vr + 32][vc4])   = gv1;
    *reinterpret_cast<int4*>(&Vs[vr + 64][vc4])   = gv2;
    *reinterpret_cast<int4*>(&Vs[vr + 96][vc4])   = gv3;
    __syncthreads();

    // ---- issue tile t+1 loads (latency hides under compute below) ----
    if (t + 1 < tend){
      const int kn = (t + 1) * 64;
      gk0 = *reinterpret_cast<const int4*>(&Kp[(size_t)(kn + kr)       * NQKV + kc4]);
      gk1 = *reinterpret_cast<const int4*>(&Kp[(size_t)(kn + kr + 16)  * NQKV + kc4]);
      gk2 = *reinterpret_cast<const int4*>(&Kp[(size_t)(kn + kr + 32)  * NQKV + kc4]);
      gk3 = *reinterpret_cast<const int4*>(&Kp[(size_t)(kn + kr + 48)  * NQKV + kc4]);
      gv0 = *reinterpret_cast<const int4*>(&Vp[(size_t)(vr)       * T_SEQ + kn + vc4]);
      gv1 = *reinterpret_cast<const int4*>(&Vp[(size_t)(vr + 32)  * T_SEQ + kn + vc4]);
      gv2 = *reinterpret_cast<const int4*>(&Vp[(size_t)(vr + 64)  * T_SEQ + kn + vc4]);
      gv3 = *reinterpret_cast<const int4*>(&Vp[(size_t)(vr + 96)  * T_SEQ + kn + vc4]);
    }

    const int kv0 = t * 64;
    if (kv0 <= qw + 31){                     // tile has unmasked work for this wave
      // ---- S^T = K Q^T (Q pre-scaled): lane holds S[kv][q=qw+l31] ----
      f32x16 s[2];
      #pragma unroll
      for (int r = 0; r < 16; ++r){ s[0][r] = 0.f; s[1][r] = 0.f; }
      __builtin_amdgcn_s_setprio(1);
      #pragma unroll
      for (int c4 = 0; c4 < 8; ++c4){
        bf16x8 k0 = *reinterpret_cast<const bf16x8*>(&Ks[l31][c4 * 16 + hi * 8]);
        bf16x8 k1 = *reinterpret_cast<const bf16x8*>(&Ks[32 + l31][c4 * 16 + hi * 8]);
        s[0] = __builtin_amdgcn_mfma_f32_32x32x16_bf16(k0, qf[c4], s[0], 0, 0, 0);
        s[1] = __builtin_amdgcn_mfma_f32_32x32x16_bf16(k1, qf[c4], s[1], 0, 0, 0);
      }
      __builtin_amdgcn_s_setprio(0);

      // ---- causal mask (diagonal tiles only; interior: no scale work) ----
      const int qg = qw + l31;
      if (kv0 + 63 > qw){
        #pragma unroll
        for (int blk = 0; blk < 2; ++blk)
          #pragma unroll
          for (int r = 0; r < 16; ++r){
            int kg = kv0 + 32 * blk + (r & 3) + 8 * (r >> 2) + 4 * hi;
            s[blk][r] = (kg <= qg) ? s[blk][r] : -__builtin_inff();
          }
      }

      // ---- row max: tree over own 32 + 1 cross-half shuffle ----
      float t8[8];
      #pragma unroll
      for (int blk = 0; blk < 2; ++blk)
        #pragma unroll
        for (int j = 0; j < 4; ++j)
          t8[blk * 4 + j] = fmaxf(fmaxf(s[blk][4*j], s[blk][4*j+1]),
                                  fmaxf(s[blk][4*j+2], s[blk][4*j+3]));
      float pm = fmaxf(fmaxf(fmaxf(t8[0], t8[1]), fmaxf(t8[2], t8[3])),
                       fmaxf(fmaxf(t8[4], t8[5]), fmaxf(t8[6], t8[7])));
      pm = fmaxf(pm, __shfl_xor(pm, 32));

      // ---- deferred rescale (wave-uniform; exp2 domain, raw v_exp) ----
      if (__any(pm > mrun)){
        float mn = fmaxf(mrun, pm);
        float scf = (mrun == -__builtin_inff()) ? 0.f : ex2(mrun - mn);
        mrun = mn; lrun *= scf;
        #pragma unroll
        for (int r = 0; r < 16; ++r){
          float scr = __shfl(scf, (r & 3) + 8 * (r >> 2) + 4 * hi, 32);
          #pragma unroll
          for (int db = 0; db < 4; ++db) o[db][r] *= scr;
        }
      }

      // ---- exp2 (raw v_exp_f32) + row sum ----
      float a8[8];
      #pragma unroll
      for (int blk = 0; blk < 2; ++blk)
        #pragma unroll
        for (int j = 0; j < 4; ++j){
          float p0 = ex2(s[blk][4*j]   - mrun);
          float p1 = ex2(s[blk][4*j+1] - mrun);
          float p2 = ex2(s[blk][4*j+2] - mrun);
          float p3 = ex2(s[blk][4*j+3] - mrun);
          s[blk][4*j] = p0; s[blk][4*j+1] = p1; s[blk][4*j+2] = p2; s[blk][4*j+3] = p3;
          a8[blk * 4 + j] = (p0 + p1) + (p2 + p3);
        }
      float ls = ((a8[0] + a8[1]) + (a8[2] + a8[3])) + ((a8[4] + a8[5]) + (a8[6] + a8[7]));
      lrun += ls + __shfl_xor(ls, 32);

      // ---- O += P V : A-frags via cvt_pk + permlane32_swap ----
      __builtin_amdgcn_s_setprio(1);
      #pragma unroll
      for (int kc = 0; kc < 4; ++kc){
        const int blk = kc >> 1, base2 = (kc & 1) * 8;
        unsigned int a0 = cvtpk(s[blk][base2+0], s[blk][base2+1]);
        unsigned int b0 = cvtpk(s[blk][base2+4], s[blk][base2+5]);
        unsigned int a1 = cvtpk(s[blk][base2+2], s[blk][base2+3]);
        unsigned int b1 = cvtpk(s[blk][base2+6], s[blk][base2+7]);
        i32x2 sw0 = __builtin_amdgcn_permlane32_swap((int)a0, (int)b0, false, false);
        i32x2 sw1 = __builtin_amdgcn_permlane32_swap((int)a1, (int)b1, false, false);
        union { bf16x8 v; unsigned int u[4]; } pa;
        pa.u[0] = (unsigned int)sw0[0];   // kv 8hi+{0,1}
        pa.u[1] = (unsigned int)sw1[0];   // kv 8hi+{2,3}
        pa.u[2] = (unsigned int)sw0[1];   // kv 8hi+{4,5}
        pa.u[3] = (unsigned int)sw1[1];   // kv 8hi+{6,7}
        #pragma unroll
        for (int db = 0; db < 4; ++db){
          bf16x8 vf = *reinterpret_cast<const bf16x8*>(
              &Vs[db * 32 + l31][kc * 16 + hi * 8]);
          o[db] = __builtin_amdgcn_mfma_f32_32x32x16_bf16(pa.v, vf, o[db], 0, 0, 0);
        }
      }
      __builtin_amdgcn_s_setprio(0);
    }
    __syncthreads();   // Ks/Vs free for next tile's ds_writes
  }

  if (nc == 1){
    // ---- final (Q<8): O /= l; write AO in (B,T,C) bf16 ----
    float inv = 1.0f / lrun;                 // this lane's q = qw + l31
    #pragma unroll
    for (int r = 0; r < 16; ++r){
      const int crow = (r & 3) + 8 * (r >> 2) + 4 * hi;
      float ir = __shfl(inv, crow, 32);
      #pragma unroll
      for (int db = 0; db < 4; ++db)
        AO[((size_t)b * T_SEQ + qw + crow) * CDIM + h * HD + db * 32 + l31] =
            f2bf(o[db][r] * ir);
    }
  } else {
    // ---- partial: unnormalized O (bf16) + m,l per row (m in log2 domain) ----
    const int slot = bh * 16 + 2 * (Q - 8) + c;
    unsigned short* OpW = Op + (size_t)slot * 128 * 128;
    #pragma unroll
    for (int r = 0; r < 16; ++r){
      const int row = wave * 32 + (r & 3) + 8 * (r >> 2) + 4 * hi;
      #pragma unroll
      for (int db = 0; db < 4; ++db)
        OpW[row * 128 + db * 32 + l31] = f2bf(o[db][r]);
    }
    if (hi == 0){
      Mp[(size_t)slot * 128 + wave * 32 + l31] = mrun;
      Lp[(size_t)slot * 128 + wave * 32 + l31] = lrun;
    }
  }
}

// ---------------- combine partials for q-blocks with nc==2 (Q=8..15) ----------------
__global__ __launch_bounds__(256) void attn_combine(
    const unsigned short* __restrict__ Op, const float* __restrict__ Mp,
    const float* __restrict__ Lp, unsigned short* __restrict__ AO)
{
  const int Q  = 8 + blockIdx.x;            // 8..15
  const int bh = blockIdx.y;
  const int b = bh / NH, h = bh % NH;
  const int slot0 = bh * 16 + 2 * (Q - 8);
  #pragma unroll
  for (int u = 0; u < 16; ++u){
    int unit = threadIdx.x + u * 256;       // 128 rows x 32 4-col groups
    int r = unit >> 5, d4 = unit & 31;
    const float m0 = Mp[(size_t)slot0 * 128 + r];
    const float m1 = Mp[(size_t)(slot0 + 1) * 128 + r];
    const float m = fmaxf(m0, m1);
    const float w0 = __builtin_amdgcn_exp2f(m0 - m);
    const float w1 = __builtin_amdgcn_exp2f(m1 - m);
    const float l = w0 * Lp[(size_t)slot0 * 128 + r]
                  + w1 * Lp[(size_t)(slot0 + 1) * 128 + r];
    const ushort4 v0 = *reinterpret_cast<const ushort4*>(
        &Op[((size_t)slot0 * 128 + r) * 128 + d4 * 4]);
    const ushort4 v1 = *reinterpret_cast<const ushort4*>(
        &Op[((size_t)(slot0 + 1) * 128 + r) * 128 + d4 * 4]);
    const float inv = 1.0f / l;
    ushort4 ov;
    ov.x = f2bf((w0 * bf2f(v0.x) + w1 * bf2f(v1.x)) * inv);
    ov.y = f2bf((w0 * bf2f(v0.y) + w1 * bf2f(v1.y)) * inv);
    ov.z = f2bf((w0 * bf2f(v0.z) + w1 * bf2f(v1.z)) * inv);
    ov.w = f2bf((w0 * bf2f(v0.w) + w1 * bf2f(v1.w)) * inv);
    *reinterpret_cast<ushort4*>(
        &AO[((size_t)b * T_SEQ + Q * 128 + r) * CDIM + h * HD + d4 * 4]) = ov;
  }
}

// ---------------- launch ----------------
extern "C" void kernel_launch(void* const* d_in, const int* in_sizes, int n_in,
                              void* d_out, int out_size, void* d_ws, size_t ws_size,
                              hipStream_t stream)
{
  (void)in_sizes; (void)n_in; (void)out_size; (void)ws_size;
  const float* x    = (const float*)d_in[0];
  const float* cosp = (const float*)d_in[1];
  const float* sinp = (const float*)d_in[2];
  const float* Wq   = (const float*)d_in[3];
  const float* Wk   = (const float*)d_in[4];
  const float* Wv   = (const float*)d_in[5];
  const float* Wo   = (const float*)d_in[6];
  float* out = (float*)d_out;

  // workspace layout: bf16 region then partials (~95 MB)
  unsigned short* xb    = (unsigned short*)d_ws;
  unsigned short* Wqkvb = xb    + (size_t)MROWS * CDIM;
  unsigned short* Wob   = Wqkvb + (size_t)NQKV * CDIM;
  unsigned short* QKVb  = Wob   + (size_t)CDIM * CDIM;
  unsigned short* Vtb   = QKVb  + (size_t)MROWS * NQKV;
  unsigned short* AO    = Vtb   + (size_t)MROWS * CDIM;
  unsigned short* Op    = AO    + (size_t)MROWS * CDIM;
  float* Mp = (float*)(Op + (size_t)NSLOT * 128 * 128);
  float* Lp = Mp + (size_t)NSLOT * 128;

  // all f32->bf16 conversions in one launch (x + 4 weight matrices)
  cvt_all<<<8448, 256, 0, stream>>>(x, Wq, Wk, Wv, Wo, xb, Wqkvb);

  // fused QKV projection + RoPE/RMSNorm(+Q-prescale) + V-transpose epilogue
  gemm_bt<1><<<dim3(MROWS / 128, NQKV / 128), 256, 0, stream>>>(
      xb, Wqkvb, QKVb, MROWS, NQKV, CDIM, cosp, sinp, Vtb);
  // causal flash attention, big-chunk split-KV -> AO (+partials)
  attn_fwd<<<576, 256, 0, stream>>>(QKVb, Vtb, AO, Op, Mp, Lp);
  attn_combine<<<dim3(8, 24), 256, 0, stream>>>(Op, Mp, Lp, AO);
  // output projection -> f32 d_out
  gemm_bt<0><<<dim3(MROWS / 128, CDIM / 128), 256, 0, stream>>>(
      AO, Wob, out, MROWS, CDIM, CDIM, nullptr, nullptr, nullptr);
}